// Round 5
// baseline (349.105 us; speedup 1.0000x reference)
//
#include <hip/hip_runtime.h>
#include <hip/hip_bf16.h>

// GCN: 3 layers of (X @ W) -> symmetric-normalized neighbor aggregation (+self loop) -> bias -> relu
// N=50000 nodes, E=640000 edges, dims 256 -> 128 -> 128 -> 16, all fp32.
// R1: 3-kernel device-wide scan (was 94 us single-block).
// R2: agg128 shfl-broadcast edge batching (73 -> ~49 us, latency fix).
// R3: split-precision bf16 MFMA GEMM (Ah*Bh + Al*Bh + Ah*Bl), ~2^-17 precision; gemms off top-5.
// R4: fill wrote 71 MB (2 x 4B random scatters/edge -> 2 dirty lines). Now single int2
//     {src, w_bits} record = 1 scatter/edge. Edge lists padded to x8 (zeroed slots, w=0):
//     agg inner loop is uniform x8 -> 8 independent 512B gathers in flight, no tail.

#define NFEAT_IN 256
#define HIDDEN   128
#define NCLS     16
#define SCAN_CHUNK 2048

typedef __attribute__((ext_vector_type(8))) short bf16x8;   // 8 bf16 in 4 VGPRs
typedef __attribute__((ext_vector_type(4))) float f32x4;

#define MFMA16(a, b, c) __builtin_amdgcn_mfma_f32_16x16x32_bf16((a), (b), (c), 0, 0, 0)

// round-to-nearest-even fp32 -> bf16 (bit pattern)
__device__ __forceinline__ unsigned short f2bf(float v) {
    union { float f; unsigned u; } a; a.f = v;
    unsigned r = a.u + 0x7fff + ((a.u >> 16) & 1);
    return (unsigned short)(r >> 16);
}
__device__ __forceinline__ float bf2f(unsigned short h) {
    union { unsigned u; float f; } b; b.u = (unsigned)h << 16;
    return b.f;
}
__device__ __forceinline__ void split1(float v, unsigned short& h, unsigned short& l) {
    h = f2bf(v);
    l = f2bf(v - bf2f(h));
}
__device__ __forceinline__ int pad8(int c) { return (c + 7) & ~7; }

// ---------------- CSR build ----------------

__global__ void count_kernel(const int* __restrict__ dst, int* __restrict__ cnt, int E) {
    int e = blockIdx.x * 256 + threadIdx.x;
    if (e < E) atomicAdd(&cnt[dst[e]], 1);
}

// Per-chunk sums of PADDED counts.
__global__ __launch_bounds__(256) void scan_partial(const int* __restrict__ cnt,
                                                    int* __restrict__ bsum, int N) {
    const int t = threadIdx.x;
    const int base = blockIdx.x * SCAN_CHUNK + t * 8;
    int s = 0;
#pragma unroll
    for (int i = 0; i < 8; i++) {
        int idx = base + i;
        if (idx < N) s += pad8(cnt[idx]);
    }
#pragma unroll
    for (int off = 32; off > 0; off >>= 1) s += __shfl_down(s, off, 64);
    __shared__ int ws[4];
    if ((t & 63) == 0) ws[t >> 6] = s;
    __syncthreads();
    if (t == 0) bsum[blockIdx.x] = ws[0] + ws[1] + ws[2] + ws[3];
}

__global__ void scan_bsum(int* __restrict__ bsum, int nb) {
    const int t = threadIdx.x;
    int orig = (t < nb) ? bsum[t] : 0;
    int v = orig;
#pragma unroll
    for (int off = 1; off < 64; off <<= 1) {
        int u = __shfl_up(v, off, 64);
        if (t >= off) v += u;
    }
    if (t < nb) bsum[t] = v - orig;
}

// row_ptr from PADDED counts; dis from real counts.
__global__ __launch_bounds__(256) void scan_final(const int* __restrict__ cnt,
                                                  const int* __restrict__ bsum,
                                                  int* __restrict__ row_ptr,
                                                  float* __restrict__ dis, int N) {
    const int t = threadIdx.x;
    const int base = blockIdx.x * SCAN_CHUNK + t * 8;
    int v[8];
    int s = 0;
#pragma unroll
    for (int i = 0; i < 8; i++) {
        int idx = base + i;
        v[i] = (idx < N) ? pad8(cnt[idx]) : 0;
        s += v[i];
    }
    __shared__ int sm[256];
    sm[t] = s;
    __syncthreads();
    for (int off = 1; off < 256; off <<= 1) {
        int u = (t >= off) ? sm[t - off] : 0;
        __syncthreads();
        sm[t] += u;
        __syncthreads();
    }
    int run = bsum[blockIdx.x] + ((t == 0) ? 0 : sm[t - 1]);
#pragma unroll
    for (int i = 0; i < 8; i++) {
        int idx = base + i;
        if (idx < N) {
            row_ptr[idx] = run;
            dis[idx] = rsqrtf((float)((run, v[i]), 0) + (float)(v[i])); // placeholder overwritten below
            run += v[i];
            if (idx == N - 1) row_ptr[N] = run;
        }
    }
    // dis needs REAL counts; recompute cleanly (separate loop keeps the scan code simple)
#pragma unroll
    for (int i = 0; i < 8; i++) {
        int idx = base + i;
        if (idx < N) dis[idx] = rsqrtf((float)(cnt[idx] + 1));
    }
}

// One int2 {src, float_bits(w)} scatter per edge.
__global__ void fill_kernel(const int* __restrict__ src, const int* __restrict__ dst,
                            const float* __restrict__ dis, const int* __restrict__ row_ptr,
                            int* __restrict__ cursor, int2* __restrict__ evec, int E) {
    int e = blockIdx.x * 256 + threadIdx.x;
    if (e >= E) return;
    int s = src[e], d = dst[e];
    int pos = atomicAdd(&cursor[d], 1);
    int idx = row_ptr[d] + pos;
    int2 ev;
    ev.x = s;
    ev.y = __float_as_int(dis[s] * dis[d]);
    evec[idx] = ev;
}

// ---------------- W prep: split fp32 W[K x 128] into bf16 hi/lo, transposed to [n][k] ----

__global__ void split_w(const float* __restrict__ W, short* __restrict__ Th,
                        short* __restrict__ Tl, int K) {
    int i = blockIdx.x * 256 + threadIdx.x;   // over K*128
    if (i >= K * 128) return;
    int k = i >> 7, n = i & 127;
    unsigned short h, l;
    split1(W[i], h, l);
    Th[(size_t)n * K + k] = (short)h;
    Tl[(size_t)n * K + k] = (short)l;
}

// ---------------- GEMM (split-bf16 MFMA): C[M x 128] = A[M x K] * B[K x 128] ----------------

template<int K>
__global__ __launch_bounds__(256) void gemm_mfma(const float* __restrict__ A,
                                                 const short* __restrict__ Bth,
                                                 const short* __restrict__ Btl,
                                                 float* __restrict__ C, int M) {
    constexpr int BM = 128, BK = 32, LDP = 40;
    __shared__ short Ash[BM][LDP], Asl[BM][LDP];
    __shared__ short Bsh[128][LDP], Bsl[128][LDP];
    const int tid = threadIdx.x;
    const int m0 = blockIdx.x * BM;
    const int w = tid >> 6, lane = tid & 63;
    const int fr = lane & 15, q = lane >> 4;
    const int tr = tid >> 1;
    const int th = (tid & 1) * 16;

    f32x4 acc[2][8];
    const f32x4 zf = {0.f, 0.f, 0.f, 0.f};
#pragma unroll
    for (int mt = 0; mt < 2; mt++)
#pragma unroll
        for (int nt = 0; nt < 8; nt++) acc[mt][nt] = zf;

    const bool arow_valid = (m0 + tr) < M;
    const float* arow = A + (size_t)(m0 + tr) * K + th;
    const short* bhrow = Bth + (size_t)tr * K + th;
    const short* blrow = Btl + (size_t)tr * K + th;

    for (int kk = 0; kk < K; kk += BK) {
        __syncthreads();
        {
            float vv[16];
            if (arow_valid) {
                const float4 v0 = *(const float4*)(arow + kk + 0);
                const float4 v1 = *(const float4*)(arow + kk + 4);
                const float4 v2 = *(const float4*)(arow + kk + 8);
                const float4 v3 = *(const float4*)(arow + kk + 12);
                vv[0] = v0.x; vv[1] = v0.y; vv[2] = v0.z; vv[3] = v0.w;
                vv[4] = v1.x; vv[5] = v1.y; vv[6] = v1.z; vv[7] = v1.w;
                vv[8] = v2.x; vv[9] = v2.y; vv[10] = v2.z; vv[11] = v2.w;
                vv[12] = v3.x; vv[13] = v3.y; vv[14] = v3.z; vv[15] = v3.w;
            } else {
#pragma unroll
                for (int i = 0; i < 16; i++) vv[i] = 0.f;
            }
            unsigned short hb[16], lb[16];
#pragma unroll
            for (int i = 0; i < 16; i++) split1(vv[i], hb[i], lb[i]);
            *(int4*)&Ash[tr][th]     = *(const int4*)&hb[0];
            *(int4*)&Ash[tr][th + 8] = *(const int4*)&hb[8];
            *(int4*)&Asl[tr][th]     = *(const int4*)&lb[0];
            *(int4*)&Asl[tr][th + 8] = *(const int4*)&lb[8];
        }
        {
            *(int4*)&Bsh[tr][th]     = *(const int4*)(bhrow + kk);
            *(int4*)&Bsh[tr][th + 8] = *(const int4*)(bhrow + kk + 8);
            *(int4*)&Bsl[tr][th]     = *(const int4*)(blrow + kk);
            *(int4*)&Bsl[tr][th + 8] = *(const int4*)(blrow + kk + 8);
        }
        __syncthreads();

        const int mr = w * 32 + fr;
        bf16x8 ah0 = *(const bf16x8*)&Ash[mr][q * 8];
        bf16x8 ah1 = *(const bf16x8*)&Ash[mr + 16][q * 8];
        bf16x8 al0 = *(const bf16x8*)&Asl[mr][q * 8];
        bf16x8 al1 = *(const bf16x8*)&Asl[mr + 16][q * 8];
#pragma unroll
        for (int nt = 0; nt < 8; nt++) {
            bf16x8 bh = *(const bf16x8*)&Bsh[nt * 16 + fr][q * 8];
            bf16x8 bl = *(const bf16x8*)&Bsl[nt * 16 + fr][q * 8];
            acc[0][nt] = MFMA16(ah0, bh, acc[0][nt]);
            acc[1][nt] = MFMA16(ah1, bh, acc[1][nt]);
            acc[0][nt] = MFMA16(al0, bh, acc[0][nt]);
            acc[1][nt] = MFMA16(al1, bh, acc[1][nt]);
            acc[0][nt] = MFMA16(ah0, bl, acc[0][nt]);
            acc[1][nt] = MFMA16(ah1, bl, acc[1][nt]);
        }
    }

#pragma unroll
    for (int mt = 0; mt < 2; mt++) {
        const int rowb = m0 + w * 32 + mt * 16 + q * 4;
#pragma unroll
        for (int r = 0; r < 4; r++) {
            const int row = rowb + r;
            if (row < M) {
#pragma unroll
                for (int nt = 0; nt < 8; nt++)
                    C[(size_t)row * 128 + nt * 16 + fr] = acc[mt][nt][r];
            }
        }
    }
}

// GEMM: C[M x 16] = A[M x 128] * B[128 x 16]. 16 rows/block, 256 threads (16x16).
__global__ __launch_bounds__(256) void gemm_n16(const float* __restrict__ A,
                                                const float* __restrict__ B,
                                                float* __restrict__ C, int M) {
    __shared__ float As[16][130];
    __shared__ float Bs[128][16];
    const int tid = threadIdx.x;
    const int m0 = blockIdx.x * 16;
#pragma unroll
    for (int t = 0; t < 2; t++) {
        int f4 = tid + t * 256;
        int r = f4 >> 5;
        int c4 = (f4 & 31) * 4;
        float4 v = make_float4(0.f, 0.f, 0.f, 0.f);
        if (m0 + r < M) v = *(const float4*)(A + (size_t)(m0 + r) * 128 + c4);
        As[r][c4] = v.x; As[r][c4 + 1] = v.y; As[r][c4 + 2] = v.z; As[r][c4 + 3] = v.w;
        int bk = f4 >> 2;
        int bn = (f4 & 3) * 4;
        float4 bv = *(const float4*)(B + (size_t)bk * 16 + bn);
        *(float4*)&Bs[bk][bn] = bv;
    }
    __syncthreads();
    const int r = tid >> 4, f = tid & 15;
    float acc = 0.f;
#pragma unroll 8
    for (int k = 0; k < 128; k++) acc += As[r][k] * Bs[k][f];
    if (m0 + r < M) C[(size_t)(m0 + r) * 16 + f] = acc;
}

// ---------------- Aggregation (pull, padded CSR, int2 edge records) ----------------
// One wave per node; lane covers feats [2*lane, 2*lane+1]. Edge count is a multiple
// of 8 -> uniform x8 inner unroll, 8 independent row gathers in flight, no tail.
__global__ __launch_bounds__(256) void agg128(const float* __restrict__ T,
                                              const int* __restrict__ row_ptr,
                                              const int2* __restrict__ evec,
                                              const float* __restrict__ dis,
                                              const float* __restrict__ bias,
                                              float* __restrict__ Hout, int N, int relu) {
    const int node = (blockIdx.x * 256 + threadIdx.x) >> 6;
    const int lane = threadIdx.x & 63;
    if (node >= N) return;
    const float d = dis[node];
    const float self_w = d * d;
    const float2 tself = *(const float2*)(T + (size_t)node * 128 + lane * 2);
    float a0 = self_w * tself.x;
    float a1 = self_w * tself.y;
    const int e0 = row_ptr[node], e1 = row_ptr[node + 1];
    const int cnt = e1 - e0;   // multiple of 8

    for (int base = 0; base < cnt; base += 64) {
        const int nb = min(64, cnt - base);   // multiple of 8
        int   idx = 0;
        float w   = 0.f;
        if (lane < nb) {
            int2 ew = evec[e0 + base + lane];
            idx = ew.x;
            w   = __int_as_float(ew.y);
        }
        for (int j = 0; j < nb; j += 8) {
            int s[8]; float ww[8];
#pragma unroll
            for (int u = 0; u < 8; u++) {
                s[u]  = __shfl(idx, j + u, 64);
                ww[u] = __shfl(w,   j + u, 64);
            }
            float2 r[8];
#pragma unroll
            for (int u = 0; u < 8; u++)
                r[u] = *(const float2*)(T + (size_t)s[u] * 128 + lane * 2);
#pragma unroll
            for (int u = 0; u < 8; u++) {
                a0 += ww[u] * r[u].x;
                a1 += ww[u] * r[u].y;
            }
        }
    }
    const float2 bv = *(const float2*)(bias + lane * 2);
    a0 += bv.x;
    a1 += bv.y;
    if (relu) { a0 = fmaxf(a0, 0.f); a1 = fmaxf(a1, 0.f); }
    *(float2*)(Hout + (size_t)node * 128 + lane * 2) = make_float2(a0, a1);
}

// 16 features: one thread per (node, feat).
__global__ void agg16(const float* __restrict__ T,
                      const int* __restrict__ row_ptr,
                      const int2* __restrict__ evec,
                      const float* __restrict__ dis,
                      const float* __restrict__ bias,
                      float* __restrict__ out, int N) {
    const int t = blockIdx.x * 256 + threadIdx.x;
    const int node = t >> 4;
    const int f = t & 15;
    if (node >= N) return;
    const float d = dis[node];
    float acc = d * d * T[(size_t)node * 16 + f];
    const int e0 = row_ptr[node], e1 = row_ptr[node + 1];
    for (int e = e0; e < e1; ++e) {
        int2 ew = evec[e];
        acc += __int_as_float(ew.y) * T[(size_t)ew.x * 16 + f];
    }
    out[(size_t)node * 16 + f] = acc + bias[f];
}

// ---------------- launch ----------------

extern "C" void kernel_launch(void* const* d_in, const int* in_sizes, int n_in,
                              void* d_out, int out_size, void* d_ws, size_t ws_size,
                              hipStream_t stream) {
    const float* x  = (const float*)d_in[0];
    const int*   ei = (const int*)d_in[1];
    const float* W1 = (const float*)d_in[2];
    const float* b1 = (const float*)d_in[3];
    const float* W2 = (const float*)d_in[4];
    const float* b2 = (const float*)d_in[5];
    const float* W3 = (const float*)d_in[6];
    const float* b3 = (const float*)d_in[7];
    float* out = (float*)d_out;

    const int N = in_sizes[0] / NFEAT_IN;   // 50000
    const int E = in_sizes[1] / 2;          // 640000
    const int* src = ei;
    const int* dst = ei + E;
    const size_t EP = (size_t)E + 8 * (size_t)N;   // padded edge capacity

    char* p = (char*)d_ws;
    auto alloc = [&](size_t bytes) -> void* {
        void* r = (void*)p;
        p += (bytes + 255) & ~(size_t)255;
        return r;
    };
    int*   cnt     = (int*)alloc((size_t)N * 4);
    int*   row_ptr = (int*)alloc(((size_t)N + 1) * 4);
    int*   cursor  = (int*)alloc((size_t)N * 4);
    float* dis     = (float*)alloc((size_t)N * 4);
    int*   bsum    = (int*)alloc(64 * 4);
    int2*  evec    = (int2*)alloc(EP * 8);
    short* Bt1h    = (short*)alloc((size_t)NFEAT_IN * 128 * 2);
    short* Bt1l    = (short*)alloc((size_t)NFEAT_IN * 128 * 2);
    short* Bt2h    = (short*)alloc((size_t)HIDDEN * 128 * 2);
    short* Bt2l    = (short*)alloc((size_t)HIDDEN * 128 * 2);
    float* T       = (float*)alloc((size_t)N * 128 * 4);
    float* H       = (float*)alloc((size_t)N * 128 * 4);

    hipMemsetAsync(cnt, 0, (size_t)N * 4, stream);
    hipMemsetAsync(cursor, 0, (size_t)N * 4, stream);
    hipMemsetAsync(evec, 0, EP * 8, stream);   // padded slots -> {0, w=0.0f}

    const int eb = (E + 255) / 256;
    const int nchunks = (N + SCAN_CHUNK - 1) / SCAN_CHUNK;

    count_kernel<<<eb, 256, 0, stream>>>(dst, cnt, E);
    scan_partial<<<nchunks, 256, 0, stream>>>(cnt, bsum, N);
    scan_bsum<<<1, 64, 0, stream>>>(bsum, nchunks);
    scan_final<<<nchunks, 256, 0, stream>>>(cnt, bsum, row_ptr, dis, N);
    fill_kernel<<<eb, 256, 0, stream>>>(src, dst, dis, row_ptr, cursor, evec, E);

    split_w<<<(NFEAT_IN * 128 + 255) / 256, 256, 0, stream>>>(W1, Bt1h, Bt1l, NFEAT_IN);
    split_w<<<(HIDDEN * 128 + 255) / 256, 256, 0, stream>>>(W2, Bt2h, Bt2l, HIDDEN);

    const int gemm_blocks = (N + 127) / 128;
    const int agg128_blocks = (N + 3) / 4;

    // Layer 1
    gemm_mfma<NFEAT_IN><<<gemm_blocks, 256, 0, stream>>>(x, Bt1h, Bt1l, T, N);
    agg128<<<agg128_blocks, 256, 0, stream>>>(T, row_ptr, evec, dis, b1, H, N, 1);

    // Layer 2
    gemm_mfma<HIDDEN><<<gemm_blocks, 256, 0, stream>>>(H, Bt2h, Bt2l, T, N);
    agg128<<<agg128_blocks, 256, 0, stream>>>(T, row_ptr, evec, dis, b2, H, N, 1);

    // Layer 3
    gemm_n16<<<(N + 15) / 16, 256, 0, stream>>>(H, W3, T, N);
    agg16<<<(N * 16 + 255) / 256, 256, 0, stream>>>(T, row_ptr, evec, dis, b3, out, N);
}

// Round 6
// 304.142 us; speedup vs baseline: 1.1478x; 1.1478x over previous
//
#include <hip/hip_runtime.h>
#include <hip/hip_bf16.h>

// GCN: 3 layers of (X @ W) -> symmetric-normalized neighbor aggregation (+self loop) -> bias -> relu
// N=50000 nodes, E=640000 edges, dims 256 -> 128 -> 128 -> 16, all fp32.
// R1: 3-kernel device-wide scan (was 94 us single-block).
// R2: agg128 shfl-broadcast edge batching (73 -> ~49 us, latency fix).
// R3: split-precision bf16 MFMA GEMM (Ah*Bh + Al*Bh + Ah*Bl), ~2^-17 precision.
// R4: int2 edge records (fill off top-5); x8 padded edge lists (neutral for agg).
// R5: agg128 is L2-miss-byte bound (FETCH 153.6 MB vs 25.6 MB array, 3.2 TB/s beyond-L2,
//     VALU 19% / HBM 47% both unsaturated). Halve the bytes: GEMM epilogue emits T in
//     bf16 (12.8 MB) -> gather rows are 256 B, one dword/lane. Layer-3 path stays fp32.

#define NFEAT_IN 256
#define HIDDEN   128
#define NCLS     16
#define SCAN_CHUNK 2048

typedef __attribute__((ext_vector_type(8))) short bf16x8;   // 8 bf16 in 4 VGPRs
typedef __attribute__((ext_vector_type(4))) float f32x4;

#define MFMA16(a, b, c) __builtin_amdgcn_mfma_f32_16x16x32_bf16((a), (b), (c), 0, 0, 0)

// round-to-nearest-even fp32 -> bf16 (bit pattern)
__device__ __forceinline__ unsigned short f2bf(float v) {
    union { float f; unsigned u; } a; a.f = v;
    unsigned r = a.u + 0x7fff + ((a.u >> 16) & 1);
    return (unsigned short)(r >> 16);
}
__device__ __forceinline__ float bf2f(unsigned short h) {
    union { unsigned u; float f; } b; b.u = (unsigned)h << 16;
    return b.f;
}
__device__ __forceinline__ void split1(float v, unsigned short& h, unsigned short& l) {
    h = f2bf(v);
    l = f2bf(v - bf2f(h));
}
__device__ __forceinline__ int pad8(int c) { return (c + 7) & ~7; }
// unpack 2 bf16 (packed little-endian in a uint) -> 2 floats
__device__ __forceinline__ float2 bfu2f(unsigned u) {
    union { unsigned a; float b; } lo, hi;
    lo.a = u << 16;
    hi.a = u & 0xffff0000u;
    return make_float2(lo.b, hi.b);
}

// ---------------- CSR build ----------------

__global__ void count_kernel(const int* __restrict__ dst, int* __restrict__ cnt, int E) {
    int e = blockIdx.x * 256 + threadIdx.x;
    if (e < E) atomicAdd(&cnt[dst[e]], 1);
}

// Per-chunk sums of PADDED counts.
__global__ __launch_bounds__(256) void scan_partial(const int* __restrict__ cnt,
                                                    int* __restrict__ bsum, int N) {
    const int t = threadIdx.x;
    const int base = blockIdx.x * SCAN_CHUNK + t * 8;
    int s = 0;
#pragma unroll
    for (int i = 0; i < 8; i++) {
        int idx = base + i;
        if (idx < N) s += pad8(cnt[idx]);
    }
#pragma unroll
    for (int off = 32; off > 0; off >>= 1) s += __shfl_down(s, off, 64);
    __shared__ int ws[4];
    if ((t & 63) == 0) ws[t >> 6] = s;
    __syncthreads();
    if (t == 0) bsum[blockIdx.x] = ws[0] + ws[1] + ws[2] + ws[3];
}

__global__ void scan_bsum(int* __restrict__ bsum, int nb) {
    const int t = threadIdx.x;
    int orig = (t < nb) ? bsum[t] : 0;
    int v = orig;
#pragma unroll
    for (int off = 1; off < 64; off <<= 1) {
        int u = __shfl_up(v, off, 64);
        if (t >= off) v += u;
    }
    if (t < nb) bsum[t] = v - orig;
}

// row_ptr from PADDED counts; dis from real counts.
__global__ __launch_bounds__(256) void scan_final(const int* __restrict__ cnt,
                                                  const int* __restrict__ bsum,
                                                  int* __restrict__ row_ptr,
                                                  float* __restrict__ dis, int N) {
    const int t = threadIdx.x;
    const int base = blockIdx.x * SCAN_CHUNK + t * 8;
    int v[8];
    int s = 0;
#pragma unroll
    for (int i = 0; i < 8; i++) {
        int idx = base + i;
        v[i] = (idx < N) ? pad8(cnt[idx]) : 0;
        s += v[i];
    }
    __shared__ int sm[256];
    sm[t] = s;
    __syncthreads();
    for (int off = 1; off < 256; off <<= 1) {
        int u = (t >= off) ? sm[t - off] : 0;
        __syncthreads();
        sm[t] += u;
        __syncthreads();
    }
    int run = bsum[blockIdx.x] + ((t == 0) ? 0 : sm[t - 1]);
#pragma unroll
    for (int i = 0; i < 8; i++) {
        int idx = base + i;
        if (idx < N) {
            row_ptr[idx] = run;
            dis[idx] = rsqrtf((float)(cnt[idx] + 1));   // real (unpadded) degree + self loop
            run += v[i];
            if (idx == N - 1) row_ptr[N] = run;
        }
    }
}

// One int2 {src, float_bits(w)} scatter per edge.
__global__ void fill_kernel(const int* __restrict__ src, const int* __restrict__ dst,
                            const float* __restrict__ dis, const int* __restrict__ row_ptr,
                            int* __restrict__ cursor, int2* __restrict__ evec, int E) {
    int e = blockIdx.x * 256 + threadIdx.x;
    if (e >= E) return;
    int s = src[e], d = dst[e];
    int pos = atomicAdd(&cursor[d], 1);
    int idx = row_ptr[d] + pos;
    int2 ev;
    ev.x = s;
    ev.y = __float_as_int(dis[s] * dis[d]);
    evec[idx] = ev;
}

// ---------------- W prep: split fp32 W[K x 128] into bf16 hi/lo, transposed to [n][k] ----

__global__ void split_w(const float* __restrict__ W, short* __restrict__ Th,
                        short* __restrict__ Tl, int K) {
    int i = blockIdx.x * 256 + threadIdx.x;   // over K*128
    if (i >= K * 128) return;
    int k = i >> 7, n = i & 127;
    unsigned short h, l;
    split1(W[i], h, l);
    Th[(size_t)n * K + k] = (short)h;
    Tl[(size_t)n * K + k] = (short)l;
}

// ---------------- GEMM (split-bf16 MFMA): Tb[M x 128] (bf16) = A[M x K] * B[K x 128] ----------------

template<int K>
__global__ __launch_bounds__(256) void gemm_mfma(const float* __restrict__ A,
                                                 const short* __restrict__ Bth,
                                                 const short* __restrict__ Btl,
                                                 unsigned short* __restrict__ Cb, int M) {
    constexpr int BM = 128, BK = 32, LDP = 40;
    __shared__ short Ash[BM][LDP], Asl[BM][LDP];
    __shared__ short Bsh[128][LDP], Bsl[128][LDP];
    const int tid = threadIdx.x;
    const int m0 = blockIdx.x * BM;
    const int w = tid >> 6, lane = tid & 63;
    const int fr = lane & 15, q = lane >> 4;
    const int tr = tid >> 1;
    const int th = (tid & 1) * 16;

    f32x4 acc[2][8];
    const f32x4 zf = {0.f, 0.f, 0.f, 0.f};
#pragma unroll
    for (int mt = 0; mt < 2; mt++)
#pragma unroll
        for (int nt = 0; nt < 8; nt++) acc[mt][nt] = zf;

    const bool arow_valid = (m0 + tr) < M;
    const float* arow = A + (size_t)(m0 + tr) * K + th;
    const short* bhrow = Bth + (size_t)tr * K + th;
    const short* blrow = Btl + (size_t)tr * K + th;

    for (int kk = 0; kk < K; kk += BK) {
        __syncthreads();
        {
            float vv[16];
            if (arow_valid) {
                const float4 v0 = *(const float4*)(arow + kk + 0);
                const float4 v1 = *(const float4*)(arow + kk + 4);
                const float4 v2 = *(const float4*)(arow + kk + 8);
                const float4 v3 = *(const float4*)(arow + kk + 12);
                vv[0] = v0.x; vv[1] = v0.y; vv[2] = v0.z; vv[3] = v0.w;
                vv[4] = v1.x; vv[5] = v1.y; vv[6] = v1.z; vv[7] = v1.w;
                vv[8] = v2.x; vv[9] = v2.y; vv[10] = v2.z; vv[11] = v2.w;
                vv[12] = v3.x; vv[13] = v3.y; vv[14] = v3.z; vv[15] = v3.w;
            } else {
#pragma unroll
                for (int i = 0; i < 16; i++) vv[i] = 0.f;
            }
            unsigned short hb[16], lb[16];
#pragma unroll
            for (int i = 0; i < 16; i++) split1(vv[i], hb[i], lb[i]);
            *(int4*)&Ash[tr][th]     = *(const int4*)&hb[0];
            *(int4*)&Ash[tr][th + 8] = *(const int4*)&hb[8];
            *(int4*)&Asl[tr][th]     = *(const int4*)&lb[0];
            *(int4*)&Asl[tr][th + 8] = *(const int4*)&lb[8];
        }
        {
            *(int4*)&Bsh[tr][th]     = *(const int4*)(bhrow + kk);
            *(int4*)&Bsh[tr][th + 8] = *(const int4*)(bhrow + kk + 8);
            *(int4*)&Bsl[tr][th]     = *(const int4*)(blrow + kk);
            *(int4*)&Bsl[tr][th + 8] = *(const int4*)(blrow + kk + 8);
        }
        __syncthreads();

        const int mr = w * 32 + fr;
        bf16x8 ah0 = *(const bf16x8*)&Ash[mr][q * 8];
        bf16x8 ah1 = *(const bf16x8*)&Ash[mr + 16][q * 8];
        bf16x8 al0 = *(const bf16x8*)&Asl[mr][q * 8];
        bf16x8 al1 = *(const bf16x8*)&Asl[mr + 16][q * 8];
#pragma unroll
        for (int nt = 0; nt < 8; nt++) {
            bf16x8 bh = *(const bf16x8*)&Bsh[nt * 16 + fr][q * 8];
            bf16x8 bl = *(const bf16x8*)&Bsl[nt * 16 + fr][q * 8];
            acc[0][nt] = MFMA16(ah0, bh, acc[0][nt]);
            acc[1][nt] = MFMA16(ah1, bh, acc[1][nt]);
            acc[0][nt] = MFMA16(al0, bh, acc[0][nt]);
            acc[1][nt] = MFMA16(al1, bh, acc[1][nt]);
            acc[0][nt] = MFMA16(ah0, bl, acc[0][nt]);
            acc[1][nt] = MFMA16(ah1, bl, acc[1][nt]);
        }
    }

    // store bf16 (RNE): C/D layout col = lane&15 (+16*nt), row = q*4 + reg
#pragma unroll
    for (int mt = 0; mt < 2; mt++) {
        const int rowb = m0 + w * 32 + mt * 16 + q * 4;
#pragma unroll
        for (int r = 0; r < 4; r++) {
            const int row = rowb + r;
            if (row < M) {
#pragma unroll
                for (int nt = 0; nt < 8; nt++)
                    Cb[(size_t)row * 128 + nt * 16 + fr] = f2bf(acc[mt][nt][r]);
            }
        }
    }
}

// GEMM: C[M x 16] = A[M x 128] * B[128 x 16]. 16 rows/block, 256 threads (16x16). fp32.
__global__ __launch_bounds__(256) void gemm_n16(const float* __restrict__ A,
                                                const float* __restrict__ B,
                                                float* __restrict__ C, int M) {
    __shared__ float As[16][130];
    __shared__ float Bs[128][16];
    const int tid = threadIdx.x;
    const int m0 = blockIdx.x * 16;
#pragma unroll
    for (int t = 0; t < 2; t++) {
        int f4 = tid + t * 256;
        int r = f4 >> 5;
        int c4 = (f4 & 31) * 4;
        float4 v = make_float4(0.f, 0.f, 0.f, 0.f);
        if (m0 + r < M) v = *(const float4*)(A + (size_t)(m0 + r) * 128 + c4);
        As[r][c4] = v.x; As[r][c4 + 1] = v.y; As[r][c4 + 2] = v.z; As[r][c4 + 3] = v.w;
        int bk = f4 >> 2;
        int bn = (f4 & 3) * 4;
        float4 bv = *(const float4*)(B + (size_t)bk * 16 + bn);
        *(float4*)&Bs[bk][bn] = bv;
    }
    __syncthreads();
    const int r = tid >> 4, f = tid & 15;
    float acc = 0.f;
#pragma unroll 8
    for (int k = 0; k < 128; k++) acc += As[r][k] * Bs[k][f];
    if (m0 + r < M) C[(size_t)(m0 + r) * 16 + f] = acc;
}

// ---------------- Aggregation (pull, padded CSR, bf16 T) ----------------
// One wave per node; lane covers feats [2*lane, 2*lane+1] packed in one uint (2 bf16).
// Edge count multiple of 8 -> uniform x8 unroll, 8 independent 256 B gathers in flight.
__global__ __launch_bounds__(256) void agg128(const unsigned short* __restrict__ Tb,
                                              const int* __restrict__ row_ptr,
                                              const int2* __restrict__ evec,
                                              const float* __restrict__ dis,
                                              const float* __restrict__ bias,
                                              float* __restrict__ Hout, int N, int relu) {
    const int node = (blockIdx.x * 256 + threadIdx.x) >> 6;
    const int lane = threadIdx.x & 63;
    if (node >= N) return;
    const float d = dis[node];
    const float self_w = d * d;
    const unsigned* Tu = (const unsigned*)Tb;   // row = 64 uints
    float2 tself = bfu2f(Tu[(size_t)node * 64 + lane]);
    float a0 = self_w * tself.x;
    float a1 = self_w * tself.y;
    const int e0 = row_ptr[node], e1 = row_ptr[node + 1];
    const int cnt = e1 - e0;   // multiple of 8

    for (int base = 0; base < cnt; base += 64) {
        const int nb = min(64, cnt - base);   // multiple of 8
        int   idx = 0;
        float w   = 0.f;
        if (lane < nb) {
            int2 ew = evec[e0 + base + lane];
            idx = ew.x;
            w   = __int_as_float(ew.y);
        }
        for (int j = 0; j < nb; j += 8) {
            int s[8]; float ww[8];
#pragma unroll
            for (int u = 0; u < 8; u++) {
                s[u]  = __shfl(idx, j + u, 64);
                ww[u] = __shfl(w,   j + u, 64);
            }
            unsigned r[8];
#pragma unroll
            for (int u = 0; u < 8; u++)
                r[u] = Tu[(size_t)s[u] * 64 + lane];
#pragma unroll
            for (int u = 0; u < 8; u++) {
                float2 f = bfu2f(r[u]);
                a0 += ww[u] * f.x;
                a1 += ww[u] * f.y;
            }
        }
    }
    const float2 bv = *(const float2*)(bias + lane * 2);
    a0 += bv.x;
    a1 += bv.y;
    if (relu) { a0 = fmaxf(a0, 0.f); a1 = fmaxf(a1, 0.f); }
    *(float2*)(Hout + (size_t)node * 128 + lane * 2) = make_float2(a0, a1);
}

// 16 features: one thread per (node, feat). fp32 path (protects output precision).
__global__ void agg16(const float* __restrict__ T,
                      const int* __restrict__ row_ptr,
                      const int2* __restrict__ evec,
                      const float* __restrict__ dis,
                      const float* __restrict__ bias,
                      float* __restrict__ out, int N) {
    const int t = blockIdx.x * 256 + threadIdx.x;
    const int node = t >> 4;
    const int f = t & 15;
    if (node >= N) return;
    const float d = dis[node];
    float acc = d * d * T[(size_t)node * 16 + f];
    const int e0 = row_ptr[node], e1 = row_ptr[node + 1];
    for (int e = e0; e < e1; ++e) {
        int2 ew = evec[e];
        acc += __int_as_float(ew.y) * T[(size_t)ew.x * 16 + f];
    }
    out[(size_t)node * 16 + f] = acc + bias[f];
}

// ---------------- launch ----------------

extern "C" void kernel_launch(void* const* d_in, const int* in_sizes, int n_in,
                              void* d_out, int out_size, void* d_ws, size_t ws_size,
                              hipStream_t stream) {
    const float* x  = (const float*)d_in[0];
    const int*   ei = (const int*)d_in[1];
    const float* W1 = (const float*)d_in[2];
    const float* b1 = (const float*)d_in[3];
    const float* W2 = (const float*)d_in[4];
    const float* b2 = (const float*)d_in[5];
    const float* W3 = (const float*)d_in[6];
    const float* b3 = (const float*)d_in[7];
    float* out = (float*)d_out;

    const int N = in_sizes[0] / NFEAT_IN;   // 50000
    const int E = in_sizes[1] / 2;          // 640000
    const int* src = ei;
    const int* dst = ei + E;
    const size_t EP = (size_t)E + 8 * (size_t)N;   // padded edge capacity

    char* p = (char*)d_ws;
    auto alloc = [&](size_t bytes) -> void* {
        void* r = (void*)p;
        p += (bytes + 255) & ~(size_t)255;
        return r;
    };
    int*   cnt     = (int*)alloc((size_t)N * 4);
    int*   row_ptr = (int*)alloc(((size_t)N + 1) * 4);
    int*   cursor  = (int*)alloc((size_t)N * 4);
    float* dis     = (float*)alloc((size_t)N * 4);
    int*   bsum    = (int*)alloc(64 * 4);
    int2*  evec    = (int2*)alloc(EP * 8);
    short* Bt1h    = (short*)alloc((size_t)NFEAT_IN * 128 * 2);
    short* Bt1l    = (short*)alloc((size_t)NFEAT_IN * 128 * 2);
    short* Bt2h    = (short*)alloc((size_t)HIDDEN * 128 * 2);
    short* Bt2l    = (short*)alloc((size_t)HIDDEN * 128 * 2);
    unsigned short* Tb = (unsigned short*)alloc((size_t)N * 128 * 2);  // bf16 pre-agg transform
    float* T3      = (float*)alloc((size_t)N * 16 * 4);                // fp32 layer-3 transform
    float* H       = (float*)alloc((size_t)N * 128 * 4);               // fp32 post-agg activations

    hipMemsetAsync(cnt, 0, (size_t)N * 4, stream);
    hipMemsetAsync(cursor, 0, (size_t)N * 4, stream);
    hipMemsetAsync(evec, 0, EP * 8, stream);   // padded slots -> {src=0, w=0.0f}

    const int eb = (E + 255) / 256;
    const int nchunks = (N + SCAN_CHUNK - 1) / SCAN_CHUNK;

    count_kernel<<<eb, 256, 0, stream>>>(dst, cnt, E);
    scan_partial<<<nchunks, 256, 0, stream>>>(cnt, bsum, N);
    scan_bsum<<<1, 64, 0, stream>>>(bsum, nchunks);
    scan_final<<<nchunks, 256, 0, stream>>>(cnt, bsum, row_ptr, dis, N);
    fill_kernel<<<eb, 256, 0, stream>>>(src, dst, dis, row_ptr, cursor, evec, E);

    split_w<<<(NFEAT_IN * 128 + 255) / 256, 256, 0, stream>>>(W1, Bt1h, Bt1l, NFEAT_IN);
    split_w<<<(HIDDEN * 128 + 255) / 256, 256, 0, stream>>>(W2, Bt2h, Bt2l, HIDDEN);

    const int gemm_blocks = (N + 127) / 128;
    const int agg128_blocks = (N + 3) / 4;

    // Layer 1: Tb = bf16(x @ W1) ; H = relu(agg(Tb) + b1)
    gemm_mfma<NFEAT_IN><<<gemm_blocks, 256, 0, stream>>>(x, Bt1h, Bt1l, Tb, N);
    agg128<<<agg128_blocks, 256, 0, stream>>>(Tb, row_ptr, evec, dis, b1, H, N, 1);

    // Layer 2: Tb = bf16(H @ W2) ; H = relu(agg(Tb) + b2)
    gemm_mfma<HIDDEN><<<gemm_blocks, 256, 0, stream>>>(H, Bt2h, Bt2l, Tb, N);
    agg128<<<agg128_blocks, 256, 0, stream>>>(Tb, row_ptr, evec, dis, b2, H, N, 1);

    // Layer 3 (fp32): T3 = H @ W3 ; out = agg(T3) + b3
    gemm_n16<<<(N + 15) / 16, 256, 0, stream>>>(H, W3, T3, N);
    agg16<<<(N * 16 + 255) / 256, 256, 0, stream>>>(T3, row_ptr, evec, dis, b3, out, N);
}

// Round 7
// 264.204 us; speedup vs baseline: 1.3213x; 1.1512x over previous
//
#include <hip/hip_runtime.h>
#include <hip/hip_bf16.h>

// GCN: 3 layers of (X @ W) -> symmetric-normalized neighbor aggregation (+self loop) -> bias -> relu
// N=50000 nodes, E=640000 edges, dims 256 -> 128 -> 128 -> 16, all fp32.
// R1: 3-kernel device-wide scan (was 94 us single-block).
// R2: agg128 shfl-broadcast edge batching (73 -> ~49 us, latency fix).
// R3: split-precision bf16 MFMA GEMM (Ah*Bh + Al*Bh + Ah*Bl), ~2^-17 precision.
// R4: int2 edge records (one 8 B scatter/edge); x8 padded edge lists.
// R5: bf16 T for the gather (halves L2-miss bytes): 349 -> 304 us; top-5 is now only the
//     harness's 256 MiB 0xAA workspace re-poison (uncontrollable).
// R6: count's atomicAdd return value IS the edge's bucket rank -> store it, drop fill's
//     cursor atomics entirely; agg16 rebuilt like agg128 (16-lane subgroups, shfl batch,
//     x8 gathers in flight); scan_bsum folded into scan_final; one split_w launch. 13 dispatches.

#define NFEAT_IN 256
#define HIDDEN   128
#define NCLS     16
#define SCAN_CHUNK 2048

typedef __attribute__((ext_vector_type(8))) short bf16x8;   // 8 bf16 in 4 VGPRs
typedef __attribute__((ext_vector_type(4))) float f32x4;

#define MFMA16(a, b, c) __builtin_amdgcn_mfma_f32_16x16x32_bf16((a), (b), (c), 0, 0, 0)

// round-to-nearest-even fp32 -> bf16 (bit pattern)
__device__ __forceinline__ unsigned short f2bf(float v) {
    union { float f; unsigned u; } a; a.f = v;
    unsigned r = a.u + 0x7fff + ((a.u >> 16) & 1);
    return (unsigned short)(r >> 16);
}
__device__ __forceinline__ float bf2f(unsigned short h) {
    union { unsigned u; float f; } b; b.u = (unsigned)h << 16;
    return b.f;
}
__device__ __forceinline__ void split1(float v, unsigned short& h, unsigned short& l) {
    h = f2bf(v);
    l = f2bf(v - bf2f(h));
}
__device__ __forceinline__ int pad8(int c) { return (c + 7) & ~7; }
// unpack 2 bf16 (packed little-endian in a uint) -> 2 floats
__device__ __forceinline__ float2 bfu2f(unsigned u) {
    union { unsigned a; float b; } lo, hi;
    lo.a = u << 16;
    hi.a = u & 0xffff0000u;
    return make_float2(lo.b, hi.b);
}

// ---------------- CSR build ----------------

// Counts per dst AND records each edge's rank within its bucket (atomicAdd return).
__global__ void count_kernel(const int* __restrict__ dst, int* __restrict__ cnt,
                             int* __restrict__ rank, int E) {
    int e = blockIdx.x * 256 + threadIdx.x;
    if (e < E) rank[e] = atomicAdd(&cnt[dst[e]], 1);
}

// Per-chunk sums of PADDED counts.
__global__ __launch_bounds__(256) void scan_partial(const int* __restrict__ cnt,
                                                    int* __restrict__ bsum, int N) {
    const int t = threadIdx.x;
    const int base = blockIdx.x * SCAN_CHUNK + t * 8;
    int s = 0;
#pragma unroll
    for (int i = 0; i < 8; i++) {
        int idx = base + i;
        if (idx < N) s += pad8(cnt[idx]);
    }
#pragma unroll
    for (int off = 32; off > 0; off >>= 1) s += __shfl_down(s, off, 64);
    __shared__ int ws[4];
    if ((t & 63) == 0) ws[t >> 6] = s;
    __syncthreads();
    if (t == 0) bsum[blockIdx.x] = ws[0] + ws[1] + ws[2] + ws[3];
}

// row_ptr from PADDED counts; dis from real counts. Each block redundantly wave-scans
// the <=64 chunk sums (replaces the separate scan_bsum launch).
__global__ __launch_bounds__(256) void scan_final(const int* __restrict__ cnt,
                                                  const int* __restrict__ bsum,
                                                  int* __restrict__ row_ptr,
                                                  float* __restrict__ dis, int N, int nchunks) {
    __shared__ int chunk_off_sm;
    const int t = threadIdx.x;
    if (t < 64) {
        int orig = (t < nchunks) ? bsum[t] : 0;
        int v = orig;
#pragma unroll
        for (int off = 1; off < 64; off <<= 1) {
            int u = __shfl_up(v, off, 64);
            if (t >= off) v += u;
        }
        if (t == (int)blockIdx.x) chunk_off_sm = v - orig;   // exclusive prefix for this chunk
    }
    const int base = blockIdx.x * SCAN_CHUNK + t * 8;
    int v[8];
    int s = 0;
#pragma unroll
    for (int i = 0; i < 8; i++) {
        int idx = base + i;
        v[i] = (idx < N) ? pad8(cnt[idx]) : 0;
        s += v[i];
    }
    __shared__ int sm[256];
    sm[t] = s;
    __syncthreads();
    for (int off = 1; off < 256; off <<= 1) {
        int u = (t >= off) ? sm[t - off] : 0;
        __syncthreads();
        sm[t] += u;
        __syncthreads();
    }
    int run = chunk_off_sm + ((t == 0) ? 0 : sm[t - 1]);
#pragma unroll
    for (int i = 0; i < 8; i++) {
        int idx = base + i;
        if (idx < N) {
            row_ptr[idx] = run;
            dis[idx] = rsqrtf((float)(cnt[idx] + 1));   // real (unpadded) degree + self loop
            run += v[i];
            if (idx == N - 1) row_ptr[N] = run;
        }
    }
}

// No atomics: idx = row_ptr[dst] + rank (precomputed). One int2 scatter per edge.
__global__ void fill_kernel(const int* __restrict__ src, const int* __restrict__ dst,
                            const int* __restrict__ rank, const float* __restrict__ dis,
                            const int* __restrict__ row_ptr, int2* __restrict__ evec, int E) {
    int e = blockIdx.x * 256 + threadIdx.x;
    if (e >= E) return;
    int s = src[e], d = dst[e];
    int idx = row_ptr[d] + rank[e];
    int2 ev;
    ev.x = s;
    ev.y = __float_as_int(dis[s] * dis[d]);
    evec[idx] = ev;
}

// ---------------- W prep: split W1 and W2 (fp32 [K x 128]) into bf16 hi/lo, transposed [n][k] ----

__global__ void split_w2(const float* __restrict__ W1, short* __restrict__ T1h, short* __restrict__ T1l,
                         const float* __restrict__ W2, short* __restrict__ T2h, short* __restrict__ T2l) {
    const int n1 = NFEAT_IN * 128;
    const int n2 = HIDDEN * 128;
    int i = blockIdx.x * 256 + threadIdx.x;
    if (i < n1) {
        int k = i >> 7, n = i & 127;
        unsigned short h, l;
        split1(W1[i], h, l);
        T1h[(size_t)n * NFEAT_IN + k] = (short)h;
        T1l[(size_t)n * NFEAT_IN + k] = (short)l;
    } else if (i < n1 + n2) {
        int j = i - n1;
        int k = j >> 7, n = j & 127;
        unsigned short h, l;
        split1(W2[j], h, l);
        T2h[(size_t)n * HIDDEN + k] = (short)h;
        T2l[(size_t)n * HIDDEN + k] = (short)l;
    }
}

// ---------------- GEMM (split-bf16 MFMA): Tb[M x 128] (bf16) = A[M x K] * B[K x 128] ----------------

template<int K>
__global__ __launch_bounds__(256) void gemm_mfma(const float* __restrict__ A,
                                                 const short* __restrict__ Bth,
                                                 const short* __restrict__ Btl,
                                                 unsigned short* __restrict__ Cb, int M) {
    constexpr int BM = 128, BK = 32, LDP = 40;
    __shared__ short Ash[BM][LDP], Asl[BM][LDP];
    __shared__ short Bsh[128][LDP], Bsl[128][LDP];
    const int tid = threadIdx.x;
    const int m0 = blockIdx.x * BM;
    const int w = tid >> 6, lane = tid & 63;
    const int fr = lane & 15, q = lane >> 4;
    const int tr = tid >> 1;
    const int th = (tid & 1) * 16;

    f32x4 acc[2][8];
    const f32x4 zf = {0.f, 0.f, 0.f, 0.f};
#pragma unroll
    for (int mt = 0; mt < 2; mt++)
#pragma unroll
        for (int nt = 0; nt < 8; nt++) acc[mt][nt] = zf;

    const bool arow_valid = (m0 + tr) < M;
    const float* arow = A + (size_t)(m0 + tr) * K + th;
    const short* bhrow = Bth + (size_t)tr * K + th;
    const short* blrow = Btl + (size_t)tr * K + th;

    for (int kk = 0; kk < K; kk += BK) {
        __syncthreads();
        {
            float vv[16];
            if (arow_valid) {
                const float4 v0 = *(const float4*)(arow + kk + 0);
                const float4 v1 = *(const float4*)(arow + kk + 4);
                const float4 v2 = *(const float4*)(arow + kk + 8);
                const float4 v3 = *(const float4*)(arow + kk + 12);
                vv[0] = v0.x; vv[1] = v0.y; vv[2] = v0.z; vv[3] = v0.w;
                vv[4] = v1.x; vv[5] = v1.y; vv[6] = v1.z; vv[7] = v1.w;
                vv[8] = v2.x; vv[9] = v2.y; vv[10] = v2.z; vv[11] = v2.w;
                vv[12] = v3.x; vv[13] = v3.y; vv[14] = v3.z; vv[15] = v3.w;
            } else {
#pragma unroll
                for (int i = 0; i < 16; i++) vv[i] = 0.f;
            }
            unsigned short hb[16], lb[16];
#pragma unroll
            for (int i = 0; i < 16; i++) split1(vv[i], hb[i], lb[i]);
            *(int4*)&Ash[tr][th]     = *(const int4*)&hb[0];
            *(int4*)&Ash[tr][th + 8] = *(const int4*)&hb[8];
            *(int4*)&Asl[tr][th]     = *(const int4*)&lb[0];
            *(int4*)&Asl[tr][th + 8] = *(const int4*)&lb[8];
        }
        {
            *(int4*)&Bsh[tr][th]     = *(const int4*)(bhrow + kk);
            *(int4*)&Bsh[tr][th + 8] = *(const int4*)(bhrow + kk + 8);
            *(int4*)&Bsl[tr][th]     = *(const int4*)(blrow + kk);
            *(int4*)&Bsl[tr][th + 8] = *(const int4*)(blrow + kk + 8);
        }
        __syncthreads();

        const int mr = w * 32 + fr;
        bf16x8 ah0 = *(const bf16x8*)&Ash[mr][q * 8];
        bf16x8 ah1 = *(const bf16x8*)&Ash[mr + 16][q * 8];
        bf16x8 al0 = *(const bf16x8*)&Asl[mr][q * 8];
        bf16x8 al1 = *(const bf16x8*)&Asl[mr + 16][q * 8];
#pragma unroll
        for (int nt = 0; nt < 8; nt++) {
            bf16x8 bh = *(const bf16x8*)&Bsh[nt * 16 + fr][q * 8];
            bf16x8 bl = *(const bf16x8*)&Bsl[nt * 16 + fr][q * 8];
            acc[0][nt] = MFMA16(ah0, bh, acc[0][nt]);
            acc[1][nt] = MFMA16(ah1, bh, acc[1][nt]);
            acc[0][nt] = MFMA16(al0, bh, acc[0][nt]);
            acc[1][nt] = MFMA16(al1, bh, acc[1][nt]);
            acc[0][nt] = MFMA16(ah0, bl, acc[0][nt]);
            acc[1][nt] = MFMA16(ah1, bl, acc[1][nt]);
        }
    }

    // store bf16 (RNE): C/D layout col = lane&15 (+16*nt), row = q*4 + reg
#pragma unroll
    for (int mt = 0; mt < 2; mt++) {
        const int rowb = m0 + w * 32 + mt * 16 + q * 4;
#pragma unroll
        for (int r = 0; r < 4; r++) {
            const int row = rowb + r;
            if (row < M) {
#pragma unroll
                for (int nt = 0; nt < 8; nt++)
                    Cb[(size_t)row * 128 + nt * 16 + fr] = f2bf(acc[mt][nt][r]);
            }
        }
    }
}

// GEMM: C[M x 16] = A[M x 128] * B[128 x 16]. 16 rows/block, 256 threads (16x16). fp32.
__global__ __launch_bounds__(256) void gemm_n16(const float* __restrict__ A,
                                                const float* __restrict__ B,
                                                float* __restrict__ C, int M) {
    __shared__ float As[16][130];
    __shared__ float Bs[128][16];
    const int tid = threadIdx.x;
    const int m0 = blockIdx.x * 16;
#pragma unroll
    for (int t = 0; t < 2; t++) {
        int f4 = tid + t * 256;
        int r = f4 >> 5;
        int c4 = (f4 & 31) * 4;
        float4 v = make_float4(0.f, 0.f, 0.f, 0.f);
        if (m0 + r < M) v = *(const float4*)(A + (size_t)(m0 + r) * 128 + c4);
        As[r][c4] = v.x; As[r][c4 + 1] = v.y; As[r][c4 + 2] = v.z; As[r][c4 + 3] = v.w;
        int bk = f4 >> 2;
        int bn = (f4 & 3) * 4;
        float4 bv = *(const float4*)(B + (size_t)bk * 16 + bn);
        *(float4*)&Bs[bk][bn] = bv;
    }
    __syncthreads();
    const int r = tid >> 4, f = tid & 15;
    float acc = 0.f;
#pragma unroll 8
    for (int k = 0; k < 128; k++) acc += As[r][k] * Bs[k][f];
    if (m0 + r < M) C[(size_t)(m0 + r) * 16 + f] = acc;
}

// ---------------- Aggregation (pull, padded CSR, bf16 T) ----------------
// One wave per node; lane covers feats [2*lane, 2*lane+1] packed in one uint (2 bf16).
// Edge count multiple of 8 -> uniform x8 unroll, 8 independent 256 B gathers in flight.
__global__ __launch_bounds__(256) void agg128(const unsigned short* __restrict__ Tb,
                                              const int* __restrict__ row_ptr,
                                              const int2* __restrict__ evec,
                                              const float* __restrict__ dis,
                                              const float* __restrict__ bias,
                                              float* __restrict__ Hout, int N, int relu) {
    const int node = (blockIdx.x * 256 + threadIdx.x) >> 6;
    const int lane = threadIdx.x & 63;
    if (node >= N) return;
    const float d = dis[node];
    const float self_w = d * d;
    const unsigned* Tu = (const unsigned*)Tb;   // row = 64 uints
    float2 tself = bfu2f(Tu[(size_t)node * 64 + lane]);
    float a0 = self_w * tself.x;
    float a1 = self_w * tself.y;
    const int e0 = row_ptr[node], e1 = row_ptr[node + 1];
    const int cnt = e1 - e0;   // multiple of 8

    for (int base = 0; base < cnt; base += 64) {
        const int nb = min(64, cnt - base);   // multiple of 8
        int   idx = 0;
        float w   = 0.f;
        if (lane < nb) {
            int2 ew = evec[e0 + base + lane];
            idx = ew.x;
            w   = __int_as_float(ew.y);
        }
        for (int j = 0; j < nb; j += 8) {
            int s[8]; float ww[8];
#pragma unroll
            for (int u = 0; u < 8; u++) {
                s[u]  = __shfl(idx, j + u, 64);
                ww[u] = __shfl(w,   j + u, 64);
            }
            unsigned r[8];
#pragma unroll
            for (int u = 0; u < 8; u++)
                r[u] = Tu[(size_t)s[u] * 64 + lane];
#pragma unroll
            for (int u = 0; u < 8; u++) {
                float2 f = bfu2f(r[u]);
                a0 += ww[u] * f.x;
                a1 += ww[u] * f.y;
            }
        }
    }
    const float2 bv = *(const float2*)(bias + lane * 2);
    a0 += bv.x;
    a1 += bv.y;
    if (relu) { a0 = fmaxf(a0, 0.f); a1 = fmaxf(a1, 0.f); }
    *(float2*)(Hout + (size_t)node * 128 + lane * 2) = make_float2(a0, a1);
}

// 16 features, fp32: 16-lane subgroup per node (4 nodes/wave). Coalesced batch edge
// loads + intra-subgroup shfl broadcast; x8 independent 64 B row gathers in flight.
__global__ __launch_bounds__(256) void agg16(const float* __restrict__ T,
                                             const int* __restrict__ row_ptr,
                                             const int2* __restrict__ evec,
                                             const float* __restrict__ dis,
                                             const float* __restrict__ bias,
                                             float* __restrict__ out, int N) {
    const int wid = (blockIdx.x * 256 + threadIdx.x) >> 6;
    const int lane = threadIdx.x & 63;
    const int sub = lane >> 4, f = lane & 15;
    const int node = wid * 4 + sub;
    if (node >= N) return;
    const float d = dis[node];
    float acc = d * d * T[(size_t)node * 16 + f];
    const int e0 = row_ptr[node], e1 = row_ptr[node + 1];
    const int cnt = e1 - e0;   // multiple of 8
    const int sbase = sub * 16;

    for (int base = 0; base < cnt; base += 16) {
        const int nb = min(16, cnt - base);   // 8 or 16
        int idx = 0; float w = 0.f;
        if (f < nb) {
            int2 ew = evec[e0 + base + f];
            idx = ew.x;
            w   = __int_as_float(ew.y);
        }
        for (int j = 0; j < nb; j += 8) {
            int s[8]; float ww[8];
#pragma unroll
            for (int u = 0; u < 8; u++) {
                s[u]  = __shfl(idx, sbase + j + u, 64);
                ww[u] = __shfl(w,   sbase + j + u, 64);
            }
            float r[8];
#pragma unroll
            for (int u = 0; u < 8; u++)
                r[u] = T[(size_t)s[u] * 16 + f];
#pragma unroll
            for (int u = 0; u < 8; u++)
                acc += ww[u] * r[u];
        }
    }
    out[(size_t)node * 16 + f] = acc + bias[f];
}

// ---------------- launch ----------------

extern "C" void kernel_launch(void* const* d_in, const int* in_sizes, int n_in,
                              void* d_out, int out_size, void* d_ws, size_t ws_size,
                              hipStream_t stream) {
    const float* x  = (const float*)d_in[0];
    const int*   ei = (const int*)d_in[1];
    const float* W1 = (const float*)d_in[2];
    const float* b1 = (const float*)d_in[3];
    const float* W2 = (const float*)d_in[4];
    const float* b2 = (const float*)d_in[5];
    const float* W3 = (const float*)d_in[6];
    const float* b3 = (const float*)d_in[7];
    float* out = (float*)d_out;

    const int N = in_sizes[0] / NFEAT_IN;   // 50000
    const int E = in_sizes[1] / 2;          // 640000
    const int* src = ei;
    const int* dst = ei + E;
    const size_t EP = (size_t)E + 8 * (size_t)N;   // padded edge capacity

    char* p = (char*)d_ws;
    auto alloc = [&](size_t bytes) -> void* {
        void* r = (void*)p;
        p += (bytes + 255) & ~(size_t)255;
        return r;
    };
    int*   cnt     = (int*)alloc((size_t)N * 4);
    int*   row_ptr = (int*)alloc(((size_t)N + 1) * 4);
    int*   rank    = (int*)alloc((size_t)E * 4);
    float* dis     = (float*)alloc((size_t)N * 4);
    int*   bsum    = (int*)alloc(64 * 4);
    int2*  evec    = (int2*)alloc(EP * 8);
    short* Bt1h    = (short*)alloc((size_t)NFEAT_IN * 128 * 2);
    short* Bt1l    = (short*)alloc((size_t)NFEAT_IN * 128 * 2);
    short* Bt2h    = (short*)alloc((size_t)HIDDEN * 128 * 2);
    short* Bt2l    = (short*)alloc((size_t)HIDDEN * 128 * 2);
    unsigned short* Tb = (unsigned short*)alloc((size_t)N * 128 * 2);  // bf16 pre-agg transform
    float* T3      = (float*)alloc((size_t)N * 16 * 4);                // fp32 layer-3 transform
    float* H       = (float*)alloc((size_t)N * 128 * 4);               // fp32 post-agg activations

    hipMemsetAsync(cnt, 0, (size_t)N * 4, stream);
    hipMemsetAsync(evec, 0, EP * 8, stream);   // padded slots -> {src=0, w=0.0f}

    const int eb = (E + 255) / 256;
    const int nchunks = (N + SCAN_CHUNK - 1) / SCAN_CHUNK;

    count_kernel<<<eb, 256, 0, stream>>>(dst, cnt, rank, E);
    scan_partial<<<nchunks, 256, 0, stream>>>(cnt, bsum, N);
    scan_final<<<nchunks, 256, 0, stream>>>(cnt, bsum, row_ptr, dis, N, nchunks);
    fill_kernel<<<eb, 256, 0, stream>>>(src, dst, rank, dis, row_ptr, evec, E);

    split_w2<<<(NFEAT_IN * 128 + HIDDEN * 128 + 255) / 256, 256, 0, stream>>>(
        W1, Bt1h, Bt1l, W2, Bt2h, Bt2l);

    const int gemm_blocks = (N + 127) / 128;
    const int agg128_blocks = (N + 3) / 4;

    // Layer 1: Tb = bf16(x @ W1) ; H = relu(agg(Tb) + b1)
    gemm_mfma<NFEAT_IN><<<gemm_blocks, 256, 0, stream>>>(x, Bt1h, Bt1l, Tb, N);
    agg128<<<agg128_blocks, 256, 0, stream>>>(Tb, row_ptr, evec, dis, b1, H, N, 1);

    // Layer 2: Tb = bf16(H @ W2) ; H = relu(agg(Tb) + b2)
    gemm_mfma<HIDDEN><<<gemm_blocks, 256, 0, stream>>>(H, Bt2h, Bt2l, Tb, N);
    agg128<<<agg128_blocks, 256, 0, stream>>>(Tb, row_ptr, evec, dis, b2, H, N, 1);

    // Layer 3 (fp32): T3 = H @ W3 ; out = agg(T3) + b3
    gemm_n16<<<(N + 15) / 16, 256, 0, stream>>>(H, W3, T3, N);
    agg16<<<(N + 15) / 16, 256, 0, stream>>>(T3, row_ptr, evec, dis, b3, out, N);
}

// Round 8
// 260.644 us; speedup vs baseline: 1.3394x; 1.0137x over previous
//
#include <hip/hip_runtime.h>
#include <hip/hip_bf16.h>

// GCN: 3 layers of (X @ W) -> symmetric-normalized neighbor aggregation (+self loop) -> bias -> relu
// N=50000 nodes, E=640000 edges, dims 256 -> 128 -> 128 -> 16, all fp32.
// R1: 3-kernel device-wide scan. R2: shfl-broadcast edge batching. R3: split-precision
// bf16 MFMA GEMM (3-MFMA hi/lo). R4: int2 edge records + x8 padded lists. R5: bf16 T
// (halves gather bytes). R6: rank-from-count (atomic-free fill), subgrouped agg16.
// R7: weightless edges. Aggregation is linear: out[d] = dis[d]*(sum T'[src] + T'[d]) + b,
//     T'[r] = dis[r]*T[r] folded into GEMM epilogues. evec = plain int (fill scatter
//     halves); pad slots -> sentinel zero row N (GEMM writes it for free: A rows >= M
//     stage as zeros); pad-slot fill folded into scan_final (evec memset launch gone).

#define NFEAT_IN 256
#define HIDDEN   128
#define NCLS     16
#define SCAN_CHUNK 2048

typedef __attribute__((ext_vector_type(8))) short bf16x8;   // 8 bf16 in 4 VGPRs
typedef __attribute__((ext_vector_type(4))) float f32x4;

#define MFMA16(a, b, c) __builtin_amdgcn_mfma_f32_16x16x32_bf16((a), (b), (c), 0, 0, 0)

// round-to-nearest-even fp32 -> bf16 (bit pattern)
__device__ __forceinline__ unsigned short f2bf(float v) {
    union { float f; unsigned u; } a; a.f = v;
    unsigned r = a.u + 0x7fff + ((a.u >> 16) & 1);
    return (unsigned short)(r >> 16);
}
__device__ __forceinline__ float bf2f(unsigned short h) {
    union { unsigned u; float f; } b; b.u = (unsigned)h << 16;
    return b.f;
}
__device__ __forceinline__ void split1(float v, unsigned short& h, unsigned short& l) {
    h = f2bf(v);
    l = f2bf(v - bf2f(h));
}
__device__ __forceinline__ int pad8(int c) { return (c + 7) & ~7; }
// unpack 2 bf16 (packed little-endian in a uint) -> 2 floats
__device__ __forceinline__ float2 bfu2f(unsigned u) {
    union { unsigned a; float b; } lo, hi;
    lo.a = u << 16;
    hi.a = u & 0xffff0000u;
    return make_float2(lo.b, hi.b);
}

// ---------------- CSR build ----------------

// Counts per dst AND records each edge's rank within its bucket (atomicAdd return).
__global__ void count_kernel(const int* __restrict__ dst, int* __restrict__ cnt,
                             int* __restrict__ rank, int E) {
    int e = blockIdx.x * 256 + threadIdx.x;
    if (e < E) rank[e] = atomicAdd(&cnt[dst[e]], 1);
}

// Per-chunk sums of PADDED counts.
__global__ __launch_bounds__(256) void scan_partial(const int* __restrict__ cnt,
                                                    int* __restrict__ bsum, int N) {
    const int t = threadIdx.x;
    const int base = blockIdx.x * SCAN_CHUNK + t * 8;
    int s = 0;
#pragma unroll
    for (int i = 0; i < 8; i++) {
        int idx = base + i;
        if (idx < N) s += pad8(cnt[idx]);
    }
#pragma unroll
    for (int off = 32; off > 0; off >>= 1) s += __shfl_down(s, off, 64);
    __shared__ int ws[4];
    if ((t & 63) == 0) ws[t >> 6] = s;
    __syncthreads();
    if (t == 0) bsum[blockIdx.x] = ws[0] + ws[1] + ws[2] + ws[3];
}

// row_ptr from PADDED counts; dis from real counts; writes sentinel N into pad slots.
// Each block redundantly wave-scans the <=64 chunk sums (no separate scan_bsum).
__global__ __launch_bounds__(256) void scan_final(const int* __restrict__ cnt,
                                                  const int* __restrict__ bsum,
                                                  int* __restrict__ row_ptr,
                                                  float* __restrict__ dis,
                                                  int* __restrict__ evec,
                                                  int N, int nchunks) {
    __shared__ int chunk_off_sm;
    const int t = threadIdx.x;
    if (t < 64) {
        int orig = (t < nchunks) ? bsum[t] : 0;
        int v = orig;
#pragma unroll
        for (int off = 1; off < 64; off <<= 1) {
            int u = __shfl_up(v, off, 64);
            if (t >= off) v += u;
        }
        if (t == (int)blockIdx.x) chunk_off_sm = v - orig;   // exclusive prefix for this chunk
    }
    const int base = blockIdx.x * SCAN_CHUNK + t * 8;
    int c[8], v[8];
    int s = 0;
#pragma unroll
    for (int i = 0; i < 8; i++) {
        int idx = base + i;
        c[i] = (idx < N) ? cnt[idx] : 0;
        v[i] = pad8(c[i]);
        s += v[i];
    }
    __shared__ int sm[256];
    sm[t] = s;
    __syncthreads();
    for (int off = 1; off < 256; off <<= 1) {
        int u = (t >= off) ? sm[t - off] : 0;
        __syncthreads();
        sm[t] += u;
        __syncthreads();
    }
    int run = chunk_off_sm + ((t == 0) ? 0 : sm[t - 1]);
#pragma unroll
    for (int i = 0; i < 8; i++) {
        int idx = base + i;
        if (idx < N) {
            row_ptr[idx] = run;
            dis[idx] = rsqrtf((float)(c[i] + 1));   // real degree + self loop
            // pad slots [run + c[i], run + v[i]) -> sentinel zero row N
            for (int j = c[i]; j < v[i]; j++) evec[run + j] = N;
            run += v[i];
            if (idx == N - 1) row_ptr[N] = run;
        }
    }
}

// No atomics, no weights: evec[row_ptr[dst] + rank] = src. One 4 B scatter per edge.
__global__ void fill_kernel(const int* __restrict__ src, const int* __restrict__ dst,
                            const int* __restrict__ rank, const int* __restrict__ row_ptr,
                            int* __restrict__ evec, int E) {
    int e = blockIdx.x * 256 + threadIdx.x;
    if (e >= E) return;
    evec[row_ptr[dst[e]] + rank[e]] = src[e];
}

// ---------------- W prep: split W1 and W2 (fp32 [K x 128]) into bf16 hi/lo, transposed [n][k] ----

__global__ void split_w2(const float* __restrict__ W1, short* __restrict__ T1h, short* __restrict__ T1l,
                         const float* __restrict__ W2, short* __restrict__ T2h, short* __restrict__ T2l) {
    const int n1 = NFEAT_IN * 128;
    const int n2 = HIDDEN * 128;
    int i = blockIdx.x * 256 + threadIdx.x;
    if (i < n1) {
        int k = i >> 7, n = i & 127;
        unsigned short h, l;
        split1(W1[i], h, l);
        T1h[(size_t)n * NFEAT_IN + k] = (short)h;
        T1l[(size_t)n * NFEAT_IN + k] = (short)l;
    } else if (i < n1 + n2) {
        int j = i - n1;
        int k = j >> 7, n = j & 127;
        unsigned short h, l;
        split1(W2[j], h, l);
        T2h[(size_t)n * HIDDEN + k] = (short)h;
        T2l[(size_t)n * HIDDEN + k] = (short)l;
    }
}

// ---------------- GEMM (split-bf16 MFMA): Tb[r] = bf16(dis[r] * (A @ B)[r]) ----------------
// Also writes the sentinel zero row N (A rows >= M stage as zeros -> acc == 0).

template<int K>
__global__ __launch_bounds__(256) void gemm_mfma(const float* __restrict__ A,
                                                 const short* __restrict__ Bth,
                                                 const short* __restrict__ Btl,
                                                 const float* __restrict__ dis,
                                                 unsigned short* __restrict__ Cb, int M) {
    constexpr int BM = 128, BK = 32, LDP = 40;
    __shared__ short Ash[BM][LDP], Asl[BM][LDP];
    __shared__ short Bsh[128][LDP], Bsl[128][LDP];
    const int tid = threadIdx.x;
    const int m0 = blockIdx.x * BM;
    const int w = tid >> 6, lane = tid & 63;
    const int fr = lane & 15, q = lane >> 4;
    const int tr = tid >> 1;
    const int th = (tid & 1) * 16;

    f32x4 acc[2][8];
    const f32x4 zf = {0.f, 0.f, 0.f, 0.f};
#pragma unroll
    for (int mt = 0; mt < 2; mt++)
#pragma unroll
        for (int nt = 0; nt < 8; nt++) acc[mt][nt] = zf;

    const bool arow_valid = (m0 + tr) < M;
    const float* arow = A + (size_t)(m0 + tr) * K + th;
    const short* bhrow = Bth + (size_t)tr * K + th;
    const short* blrow = Btl + (size_t)tr * K + th;

    for (int kk = 0; kk < K; kk += BK) {
        __syncthreads();
        {
            float vv[16];
            if (arow_valid) {
                const float4 v0 = *(const float4*)(arow + kk + 0);
                const float4 v1 = *(const float4*)(arow + kk + 4);
                const float4 v2 = *(const float4*)(arow + kk + 8);
                const float4 v3 = *(const float4*)(arow + kk + 12);
                vv[0] = v0.x; vv[1] = v0.y; vv[2] = v0.z; vv[3] = v0.w;
                vv[4] = v1.x; vv[5] = v1.y; vv[6] = v1.z; vv[7] = v1.w;
                vv[8] = v2.x; vv[9] = v2.y; vv[10] = v2.z; vv[11] = v2.w;
                vv[12] = v3.x; vv[13] = v3.y; vv[14] = v3.z; vv[15] = v3.w;
            } else {
#pragma unroll
                for (int i = 0; i < 16; i++) vv[i] = 0.f;
            }
            unsigned short hb[16], lb[16];
#pragma unroll
            for (int i = 0; i < 16; i++) split1(vv[i], hb[i], lb[i]);
            *(int4*)&Ash[tr][th]     = *(const int4*)&hb[0];
            *(int4*)&Ash[tr][th + 8] = *(const int4*)&hb[8];
            *(int4*)&Asl[tr][th]     = *(const int4*)&lb[0];
            *(int4*)&Asl[tr][th + 8] = *(const int4*)&lb[8];
        }
        {
            *(int4*)&Bsh[tr][th]     = *(const int4*)(bhrow + kk);
            *(int4*)&Bsh[tr][th + 8] = *(const int4*)(bhrow + kk + 8);
            *(int4*)&Bsl[tr][th]     = *(const int4*)(blrow + kk);
            *(int4*)&Bsl[tr][th + 8] = *(const int4*)(blrow + kk + 8);
        }
        __syncthreads();

        const int mr = w * 32 + fr;
        bf16x8 ah0 = *(const bf16x8*)&Ash[mr][q * 8];
        bf16x8 ah1 = *(const bf16x8*)&Ash[mr + 16][q * 8];
        bf16x8 al0 = *(const bf16x8*)&Asl[mr][q * 8];
        bf16x8 al1 = *(const bf16x8*)&Asl[mr + 16][q * 8];
#pragma unroll
        for (int nt = 0; nt < 8; nt++) {
            bf16x8 bh = *(const bf16x8*)&Bsh[nt * 16 + fr][q * 8];
            bf16x8 bl = *(const bf16x8*)&Bsl[nt * 16 + fr][q * 8];
            acc[0][nt] = MFMA16(ah0, bh, acc[0][nt]);
            acc[1][nt] = MFMA16(ah1, bh, acc[1][nt]);
            acc[0][nt] = MFMA16(al0, bh, acc[0][nt]);
            acc[1][nt] = MFMA16(al1, bh, acc[1][nt]);
            acc[0][nt] = MFMA16(ah0, bl, acc[0][nt]);
            acc[1][nt] = MFMA16(ah1, bl, acc[1][nt]);
        }
    }

    // store bf16 of dis[row]*acc; rows in [M, M+1) get zeros (sentinel row).
#pragma unroll
    for (int mt = 0; mt < 2; mt++) {
        const int rowb = m0 + w * 32 + mt * 16 + q * 4;
#pragma unroll
        for (int r = 0; r < 4; r++) {
            const int row = rowb + r;
            if (row <= M) {   // includes sentinel row M (acc==0 there)
                const float sc = (row < M) ? dis[row] : 0.f;
#pragma unroll
                for (int nt = 0; nt < 8; nt++)
                    Cb[(size_t)row * 128 + nt * 16 + fr] = f2bf(sc * acc[mt][nt][r]);
            }
        }
    }
}

// GEMM: T3[r] = dis[r] * (A[M x 128] @ B[128 x 16])[r]. Writes sentinel zero row M.
__global__ __launch_bounds__(256) void gemm_n16(const float* __restrict__ A,
                                                const float* __restrict__ B,
                                                const float* __restrict__ dis,
                                                float* __restrict__ C, int M) {
    __shared__ float As[16][130];
    __shared__ float Bs[128][16];
    const int tid = threadIdx.x;
    const int m0 = blockIdx.x * 16;
#pragma unroll
    for (int t = 0; t < 2; t++) {
        int f4 = tid + t * 256;
        int r = f4 >> 5;
        int c4 = (f4 & 31) * 4;
        float4 v = make_float4(0.f, 0.f, 0.f, 0.f);
        if (m0 + r < M) v = *(const float4*)(A + (size_t)(m0 + r) * 128 + c4);
        As[r][c4] = v.x; As[r][c4 + 1] = v.y; As[r][c4 + 2] = v.z; As[r][c4 + 3] = v.w;
        int bk = f4 >> 2;
        int bn = (f4 & 3) * 4;
        float4 bv = *(const float4*)(B + (size_t)bk * 16 + bn);
        *(float4*)&Bs[bk][bn] = bv;
    }
    __syncthreads();
    const int r = tid >> 4, f = tid & 15;
    float acc = 0.f;
#pragma unroll 8
    for (int k = 0; k < 128; k++) acc += As[r][k] * Bs[k][f];
    const int row = m0 + r;
    if (row <= M) {
        const float sc = (row < M) ? dis[row] : 0.f;
        C[(size_t)row * 16 + f] = sc * acc;
    }
}

// ---------------- Aggregation (pull, padded CSR, bf16 pre-scaled T') ----------------
// H[d] = relu(dis[d] * (sum_e T'[src_e] + T'[d]) + b). One wave per node; lane covers
// feats [2*lane, 2*lane+1]. x8 unroll -> 8 independent 256 B gathers in flight.
__global__ __launch_bounds__(256) void agg128(const unsigned short* __restrict__ Tb,
                                              const int* __restrict__ row_ptr,
                                              const int* __restrict__ evec,
                                              const float* __restrict__ dis,
                                              const float* __restrict__ bias,
                                              float* __restrict__ Hout, int N, int relu) {
    const int node = (blockIdx.x * 256 + threadIdx.x) >> 6;
    const int lane = threadIdx.x & 63;
    if (node >= N) return;
    const unsigned* Tu = (const unsigned*)Tb;   // row = 64 uints
    float2 tself = bfu2f(Tu[(size_t)node * 64 + lane]);
    float a0 = tself.x;
    float a1 = tself.y;
    const int e0 = row_ptr[node], e1 = row_ptr[node + 1];
    const int cnt = e1 - e0;   // multiple of 8

    for (int base = 0; base < cnt; base += 64) {
        const int nb = min(64, cnt - base);   // multiple of 8
        int idx = 0;
        if (lane < nb) idx = evec[e0 + base + lane];
        for (int j = 0; j < nb; j += 8) {
            int s[8];
#pragma unroll
            for (int u = 0; u < 8; u++) s[u] = __shfl(idx, j + u, 64);
            unsigned r[8];
#pragma unroll
            for (int u = 0; u < 8; u++)
                r[u] = Tu[(size_t)s[u] * 64 + lane];
#pragma unroll
            for (int u = 0; u < 8; u++) {
                float2 f = bfu2f(r[u]);
                a0 += f.x;
                a1 += f.y;
            }
        }
    }
    const float d = dis[node];
    const float2 bv = *(const float2*)(bias + lane * 2);
    a0 = a0 * d + bv.x;
    a1 = a1 * d + bv.y;
    if (relu) { a0 = fmaxf(a0, 0.f); a1 = fmaxf(a1, 0.f); }
    *(float2*)(Hout + (size_t)node * 128 + lane * 2) = make_float2(a0, a1);
}

// 16 features, fp32 pre-scaled T3': 16-lane subgroup per node (4 nodes/wave).
__global__ __launch_bounds__(256) void agg16(const float* __restrict__ T,
                                             const int* __restrict__ row_ptr,
                                             const int* __restrict__ evec,
                                             const float* __restrict__ dis,
                                             const float* __restrict__ bias,
                                             float* __restrict__ out, int N) {
    const int wid = (blockIdx.x * 256 + threadIdx.x) >> 6;
    const int lane = threadIdx.x & 63;
    const int sub = lane >> 4, f = lane & 15;
    const int node = wid * 4 + sub;
    if (node >= N) return;
    float acc = T[(size_t)node * 16 + f];
    const int e0 = row_ptr[node], e1 = row_ptr[node + 1];
    const int cnt = e1 - e0;   // multiple of 8
    const int sbase = sub * 16;

    for (int base = 0; base < cnt; base += 16) {
        const int nb = min(16, cnt - base);   // 8 or 16
        int idx = 0;
        if (f < nb) idx = evec[e0 + base + f];
        for (int j = 0; j < nb; j += 8) {
            int s[8];
#pragma unroll
            for (int u = 0; u < 8; u++) s[u] = __shfl(idx, sbase + j + u, 64);
            float r[8];
#pragma unroll
            for (int u = 0; u < 8; u++)
                r[u] = T[(size_t)s[u] * 16 + f];
#pragma unroll
            for (int u = 0; u < 8; u++) acc += r[u];
        }
    }
    out[(size_t)node * 16 + f] = acc * dis[node] + bias[f];
}

// ---------------- launch ----------------

extern "C" void kernel_launch(void* const* d_in, const int* in_sizes, int n_in,
                              void* d_out, int out_size, void* d_ws, size_t ws_size,
                              hipStream_t stream) {
    const float* x  = (const float*)d_in[0];
    const int*   ei = (const int*)d_in[1];
    const float* W1 = (const float*)d_in[2];
    const float* b1 = (const float*)d_in[3];
    const float* W2 = (const float*)d_in[4];
    const float* b2 = (const float*)d_in[5];
    const float* W3 = (const float*)d_in[6];
    const float* b3 = (const float*)d_in[7];
    float* out = (float*)d_out;

    const int N = in_sizes[0] / NFEAT_IN;   // 50000
    const int E = in_sizes[1] / 2;          // 640000
    const int* src = ei;
    const int* dst = ei + E;
    const size_t EP = (size_t)E + 8 * (size_t)N;   // padded edge capacity

    char* p = (char*)d_ws;
    auto alloc = [&](size_t bytes) -> void* {
        void* r = (void*)p;
        p += (bytes + 255) & ~(size_t)255;
        return r;
    };
    int*   cnt     = (int*)alloc((size_t)N * 4);
    int*   row_ptr = (int*)alloc(((size_t)N + 1) * 4);
    int*   rank    = (int*)alloc((size_t)E * 4);
    float* dis     = (float*)alloc((size_t)N * 4);
    int*   bsum    = (int*)alloc(64 * 4);
    int*   evec    = (int*)alloc(EP * 4);
    short* Bt1h    = (short*)alloc((size_t)NFEAT_IN * 128 * 2);
    short* Bt1l    = (short*)alloc((size_t)NFEAT_IN * 128 * 2);
    short* Bt2h    = (short*)alloc((size_t)HIDDEN * 128 * 2);
    short* Bt2l    = (short*)alloc((size_t)HIDDEN * 128 * 2);
    unsigned short* Tb = (unsigned short*)alloc(((size_t)N + 1) * 128 * 2); // bf16 T' (+sentinel row)
    float* T3      = (float*)alloc(((size_t)N + 16) * 16 * 4);              // fp32 T3' (+sentinel row)
    float* H       = (float*)alloc((size_t)N * 128 * 4);                    // fp32 post-agg activations

    hipMemsetAsync(cnt, 0, (size_t)N * 4, stream);

    const int eb = (E + 255) / 256;
    const int nchunks = (N + SCAN_CHUNK - 1) / SCAN_CHUNK;

    count_kernel<<<eb, 256, 0, stream>>>(dst, cnt, rank, E);
    scan_partial<<<nchunks, 256, 0, stream>>>(cnt, bsum, N);
    scan_final<<<nchunks, 256, 0, stream>>>(cnt, bsum, row_ptr, dis, evec, N, nchunks);
    fill_kernel<<<eb, 256, 0, stream>>>(src, dst, rank, row_ptr, evec, E);

    split_w2<<<(NFEAT_IN * 128 + HIDDEN * 128 + 255) / 256, 256, 0, stream>>>(
        W1, Bt1h, Bt1l, W2, Bt2h, Bt2l);

    const int gemm_blocks = (N + 1 + 127) / 128;   // cover sentinel row N
    const int agg128_blocks = (N + 3) / 4;

    // Layer 1: Tb = bf16(dis .* (x @ W1)) ; H = relu(dis .* agg(Tb) + b1)
    gemm_mfma<NFEAT_IN><<<gemm_blocks, 256, 0, stream>>>(x, Bt1h, Bt1l, dis, Tb, N);
    agg128<<<agg128_blocks, 256, 0, stream>>>(Tb, row_ptr, evec, dis, b1, H, N, 1);

    // Layer 2
    gemm_mfma<HIDDEN><<<gemm_blocks, 256, 0, stream>>>(H, Bt2h, Bt2l, dis, Tb, N);
    agg128<<<agg128_blocks, 256, 0, stream>>>(Tb, row_ptr, evec, dis, b2, H, N, 1);

    // Layer 3 (fp32)
    gemm_n16<<<(N + 1 + 15) / 16, 256, 0, stream>>>(H, W3, dis, T3, N);
    agg16<<<(N + 15) / 16, 256, 0, stream>>>(T3, row_ptr, evec, dis, b3, out, N);
}